// Round 3
// baseline (14446.671 us; speedup 1.0000x reference)
//
#include <hip/hip_runtime.h>

// Problem constants
#define Bn 4096
#define Tn 256
#define Dn 64
#define Hn 256

#define BT  32        // batch rows per workgroup
#define NTH 512       // 8 waves
#define NWG 128       // 4096/32
#define LDH 264       // padded bf16 LDS stride for h tiles

typedef __attribute__((ext_vector_type(4))) float f32x4;
typedef __attribute__((ext_vector_type(8))) short bf16x8;

#define MFMA16(a,b,c) __builtin_amdgcn_mfma_f32_16x16x32_bf16((a),(b),(c),0,0,0)

// bf16 weight copies in d_ws (element offsets), FRAGMENT-CONTIGUOUS layout:
// matrix [R x K] stored as blocks (cb = row/16, k = col/32) of 512 elems;
// within a block, element (q, r16, e) at offset q*128 + r16*8 + e holds
// W[cb*16 + r16][k*32 + q*8 + e]. A wave's B-frag load for (cb,k) is then
// one contiguous 1KB burst: base + ((cb*nkb + k)*512 + lane*8).
#define OFF_WIH1 0
#define OFF_WHH1 49152
#define OFF_WIH2 245760
#define OFF_WHH2 442368
#define OFF_WFC  638976
#define W_TOTAL  655360

__device__ __forceinline__ short f2b(float f){
  union { float fv; unsigned u; } v; v.fv = f;
  unsigned r = v.u + 0x7fffu + ((v.u >> 16) & 1u);   // RNE
  return (short)(r >> 16);
}
__device__ __forceinline__ float sigm(float x){ return 1.f/(1.f+__expf(-x)); }
__device__ __forceinline__ float tanh_s(float x){ float e=__expf(2.f*x); return 1.f - 2.f/(e+1.f); }

__global__ void prep_weights(const float* __restrict__ Wih1, const float* __restrict__ Whh1,
                             const float* __restrict__ Wih2, const float* __restrict__ Whh2,
                             const float* __restrict__ Wfc, short* __restrict__ wsb){
  for (int i = blockIdx.x*blockDim.x + threadIdx.x; i < W_TOTAL; i += gridDim.x*blockDim.x){
    const float* src; int local, K, s;
    if (i < OFF_WHH1)      { src = Wih1; local = i - OFF_WIH1; K = 64;  s = 1; }
    else if (i < OFF_WIH2) { src = Whh1; local = i - OFF_WHH1; K = 256; s = 3; }
    else if (i < OFF_WHH2) { src = Wih2; local = i - OFF_WIH2; K = 256; s = 3; }
    else if (i < OFF_WFC)  { src = Whh2; local = i - OFF_WHH2; K = 256; s = 3; }
    else                   { src = Wfc;  local = i - OFF_WFC;  K = 256; s = 3; }
    const int blk = local >> 9, e9 = local & 511;
    const int q = e9 >> 7, r16 = (e9 >> 3) & 15, e = e9 & 7;
    const int cb = blk >> s, k = blk & ((1 << s) - 1);
    const int row = cb*16 + r16, col = k*32 + q*8 + e;
    wsb[i] = f2b(src[row*K + col]);
  }
}

__global__ __launch_bounds__(NTH, 2) void gru_fused(
    const float* __restrict__ x,
    const float* __restrict__ h1_in, const float* __restrict__ h2_in,
    const float* __restrict__ b_ih1, const float* __restrict__ b_hh1,
    const float* __restrict__ b_ih2, const float* __restrict__ b_hh2,
    const float* __restrict__ b_fc,
    const short* __restrict__ wsb,
    float* __restrict__ out)
{
  __shared__ short H1[2][BT*LDH];   // double-buffered h1 (bf16)
  __shared__ short H2[2][BT*LDH];   // double-buffered h2 (bf16)

  const int tid = (int)threadIdx.x;
  const int w   = tid >> 6;     // wave 0..7
  const int l   = tid & 63;
  const int q   = l >> 4;       // 0..3
  const int r16 = l & 15;
  const int b0  = (int)blockIdx.x * BT;

  const short* __restrict__ Wih1f = wsb + OFF_WIH1;
  const short* __restrict__ Whh1f = wsb + OFF_WHH1;
  const short* __restrict__ Wih2f = wsb + OFF_WIH2;
  const short* __restrict__ Whh2f = wsb + OFF_WHH2;
  const short* __restrict__ Wfcf  = wsb + OFF_WFC;

  // --- bias preload (per-lane: column fixed for the whole run) ---
  float bi1[2][3], bh1v[2][3], bi2[2][3], bh2v[2][3];
#pragma unroll
  for (int c=0;c<2;++c)
#pragma unroll
    for (int g=0;g<3;++g){
      const int col = g*Hn + (2*w+c)*16 + r16;
      bi1 [c][g] = b_ih1[col];  bh1v[c][g] = b_hh1[col];
      bi2 [c][g] = b_ih2[col];  bh2v[c][g] = b_hh2[col];
    }
  const float bfc = b_fc[(w&3)*16 + r16];

  // --- h state: fp32 in registers (D-frag layout), bf16 copies in LDS buf 0 ---
  float h1s[2][2][4], h2s[2][2][4];
#pragma unroll
  for (int rt=0;rt<2;++rt)
#pragma unroll
    for (int c=0;c<2;++c)
#pragma unroll
      for (int j=0;j<4;++j){
        const int row = rt*16 + q*4 + j;
        const int col = (2*w+c)*16 + r16;
        const float v1 = h1_in[(size_t)(b0+row)*Hn + col];
        const float v2 = h2_in[(size_t)(b0+row)*Hn + col];
        h1s[rt][c][j] = v1;  h2s[rt][c][j] = v2;
        H1[0][row*LDH + col] = f2b(v1);
        H2[0][row*LDH + col] = f2b(v2);
      }
  __syncthreads();

  const f32x4 z4 = {0.f,0.f,0.f,0.f};

  for (int t=0; t<Tn; ++t){
    const int cur = t & 1, nxt = cur ^ 1;

    // ---- x_t A-fragments straight from global (no LDS, no barrier) ----
    bf16x8 ax[2][2];   // [rt][k]
#pragma unroll
    for (int rt=0;rt<2;++rt)
#pragma unroll
      for (int k=0;k<2;++k){
        const float* xp = x + ((size_t)(b0 + rt*16 + r16)*Tn + t)*Dn + k*32 + q*8;
        const float4 v0 = *(const float4*)xp;
        const float4 v1 = *(const float4*)(xp+4);
        bf16x8 a;
        a[0]=f2b(v0.x); a[1]=f2b(v0.y); a[2]=f2b(v0.z); a[3]=f2b(v0.w);
        a[4]=f2b(v1.x); a[5]=f2b(v1.y); a[6]=f2b(v1.z); a[7]=f2b(v1.w);
        ax[rt][k] = a;
      }

    // ---- layer 1: gi1 = x@Wih1^T, gh1 = h1@Whh1^T ----
    f32x4 gi[2][2][3], gh[2][2][3];
#pragma unroll
    for (int rt=0;rt<2;++rt)
#pragma unroll
      for (int c=0;c<2;++c)
#pragma unroll
        for (int g=0;g<3;++g){ gi[rt][c][g]=z4; gh[rt][c][g]=z4; }

#pragma unroll
    for (int k=0;k<2;++k)
#pragma unroll
      for (int c=0;c<2;++c)
#pragma unroll
        for (int g=0;g<3;++g){
          const int cb = g*16 + 2*w + c;
          const bf16x8 bx = *(const bf16x8*)&Wih1f[(((cb<<1)+k)<<9) + (l<<3)];
          gi[0][c][g] = MFMA16(ax[0][k], bx, gi[0][c][g]);
          gi[1][c][g] = MFMA16(ax[1][k], bx, gi[1][c][g]);
        }

#pragma unroll
    for (int k=0;k<8;++k){
      const bf16x8 a0 = *(const bf16x8*)&H1[cur][(r16   )*LDH + k*32 + q*8];
      const bf16x8 a1 = *(const bf16x8*)&H1[cur][(16+r16)*LDH + k*32 + q*8];
#pragma unroll
      for (int c=0;c<2;++c)
#pragma unroll
        for (int g=0;g<3;++g){
          const int cb = g*16 + 2*w + c;
          const bf16x8 bb = *(const bf16x8*)&Whh1f[(((cb<<3)+k)<<9) + (l<<3)];
          gh[0][c][g] = MFMA16(a0, bb, gh[0][c][g]);
          gh[1][c][g] = MFMA16(a1, bb, gh[1][c][g]);
        }
    }

    // ---- gates layer 1 (fp32), write h1 into H1[nxt] ----
#pragma unroll
    for (int rt=0;rt<2;++rt)
#pragma unroll
      for (int c=0;c<2;++c){
        const int colb = (2*w+c)*16 + r16;
#pragma unroll
        for (int j=0;j<4;++j){
          const float rr = sigm(gi[rt][c][0][j]+bi1[c][0] + gh[rt][c][0][j]+bh1v[c][0]);
          const float zz = sigm(gi[rt][c][1][j]+bi1[c][1] + gh[rt][c][1][j]+bh1v[c][1]);
          const float nn = tanh_s(gi[rt][c][2][j]+bi1[c][2] + rr*(gh[rt][c][2][j]+bh1v[c][2]));
          const float hv = (1.f-zz)*nn + zz*h1s[rt][c][j];
          h1s[rt][c][j] = hv;
          H1[nxt][(rt*16 + q*4 + j)*LDH + colb] = f2b(hv);
        }
      }
    __syncthreads();   // B1: new h1 visible

    // ---- layer 2: gi2 = h1_new@Wih2^T, gh2 = h2@Whh2^T ----
#pragma unroll
    for (int rt=0;rt<2;++rt)
#pragma unroll
      for (int c=0;c<2;++c)
#pragma unroll
        for (int g=0;g<3;++g){ gi[rt][c][g]=z4; gh[rt][c][g]=z4; }

#pragma unroll
    for (int k=0;k<8;++k){
      const bf16x8 p0 = *(const bf16x8*)&H1[nxt][(r16   )*LDH + k*32 + q*8];
      const bf16x8 p1 = *(const bf16x8*)&H1[nxt][(16+r16)*LDH + k*32 + q*8];
      const bf16x8 s0 = *(const bf16x8*)&H2[cur][(r16   )*LDH + k*32 + q*8];
      const bf16x8 s1 = *(const bf16x8*)&H2[cur][(16+r16)*LDH + k*32 + q*8];
#pragma unroll
      for (int c=0;c<2;++c)
#pragma unroll
        for (int g=0;g<3;++g){
          const int cb = g*16 + 2*w + c;
          const bf16x8 wi = *(const bf16x8*)&Wih2f[(((cb<<3)+k)<<9) + (l<<3)];
          const bf16x8 wh = *(const bf16x8*)&Whh2f[(((cb<<3)+k)<<9) + (l<<3)];
          gi[0][c][g] = MFMA16(p0, wi, gi[0][c][g]);
          gi[1][c][g] = MFMA16(p1, wi, gi[1][c][g]);
          gh[0][c][g] = MFMA16(s0, wh, gh[0][c][g]);
          gh[1][c][g] = MFMA16(s1, wh, gh[1][c][g]);
        }
    }

    // ---- gates layer 2 (fp32), write h2 into H2[nxt] ----
#pragma unroll
    for (int rt=0;rt<2;++rt)
#pragma unroll
      for (int c=0;c<2;++c){
        const int colb = (2*w+c)*16 + r16;
#pragma unroll
        for (int j=0;j<4;++j){
          const float rr = sigm(gi[rt][c][0][j]+bi2[c][0] + gh[rt][c][0][j]+bh2v[c][0]);
          const float zz = sigm(gi[rt][c][1][j]+bi2[c][1] + gh[rt][c][1][j]+bh2v[c][1]);
          const float nn = tanh_s(gi[rt][c][2][j]+bi2[c][2] + rr*(gh[rt][c][2][j]+bh2v[c][2]));
          const float hv = (1.f-zz)*nn + zz*h2s[rt][c][j];
          h2s[rt][c][j] = hv;
          H2[nxt][(rt*16 + q*4 + j)*LDH + colb] = f2b(hv);
        }
      }
    __syncthreads();   // B2: new h2 visible

    // ---- fc head: y_t = h2_new@Wfc^T + b_fc ----
    {
      const int rtw = w >> 2, ct = w & 3;
      f32x4 acc = z4;
#pragma unroll
      for (int k=0;k<8;++k){
        const bf16x8 a = *(const bf16x8*)&H2[nxt][(rtw*16 + r16)*LDH + k*32 + q*8];
        const bf16x8 b = *(const bf16x8*)&Wfcf[(((ct<<3)+k)<<9) + (l<<3)];
        acc = MFMA16(a, b, acc);
      }
#pragma unroll
      for (int j=0;j<4;++j){
        out[((size_t)(b0 + rtw*16 + q*4 + j)*Tn + t)*Dn + ct*16 + r16] = acc[j] + bfc;
      }
    }
  } // t loop

  // ---- final states ----
  const size_t offH1 = (size_t)Bn*Tn*Dn;
  const size_t offH2 = offH1 + (size_t)Bn*Hn;
#pragma unroll
  for (int rt=0;rt<2;++rt)
#pragma unroll
    for (int c=0;c<2;++c)
#pragma unroll
      for (int j=0;j<4;++j){
        const int row = b0 + rt*16 + q*4 + j;
        const int col = (2*w+c)*16 + r16;
        out[offH1 + (size_t)row*Hn + col] = h1s[rt][c][j];
        out[offH2 + (size_t)row*Hn + col] = h2s[rt][c][j];
      }
}

extern "C" void kernel_launch(void* const* d_in, const int* in_sizes, int n_in,
                              void* d_out, int out_size, void* d_ws, size_t ws_size,
                              hipStream_t stream) {
  const float* x    = (const float*)d_in[0];
  const float* h1i  = (const float*)d_in[1];
  const float* h2i  = (const float*)d_in[2];
  const float* Wih1 = (const float*)d_in[3];
  const float* Whh1 = (const float*)d_in[4];
  const float* bih1 = (const float*)d_in[5];
  const float* bhh1 = (const float*)d_in[6];
  const float* Wih2 = (const float*)d_in[7];
  const float* Whh2 = (const float*)d_in[8];
  const float* bih2 = (const float*)d_in[9];
  const float* bhh2 = (const float*)d_in[10];
  const float* Wfc  = (const float*)d_in[11];
  const float* bfc  = (const float*)d_in[12];
  short* wsb = (short*)d_ws;
  float* out = (float*)d_out;

  hipLaunchKernelGGL(prep_weights, dim3(512), dim3(256), 0, stream,
                     Wih1, Whh1, Wih2, Whh2, Wfc, wsb);
  hipLaunchKernelGGL(gru_fused, dim3(NWG), dim3(NTH), 0, stream,
                     x, h1i, h2i, bih1, bhh1, bih2, bhh2, bfc, wsb, out);
}